// Round 11
// baseline (213.314 us; speedup 1.0000x reference)
//
#include <hip/hip_runtime.h>
#include <cmath>

#define TT 1024
#define BB 8
#define IND 512
#define NCH 32
#define CHL 32          // TT / NCH
#define EPSV 1e-8
#define OUTHALF ((size_t)TT * BB * 4096)

// ---------------- K1: projections v,k,alpha — register-direct, NO LDS ----------
// Per 4-q group: 3 per-lane w float4 + 4 wave-uniform x float4 (VMEM pipe only),
// 48 FMA. LDS unit untouched -> FMA-bound. Same k-order + 64-k f64 chunking as
// R1/R6 -> bit-identical output.
__global__ __launch_bounds__(256)
void k1_proj(const float* __restrict__ x,
             const float* __restrict__ Wv, const float* __restrict__ bv,
             const float* __restrict__ Wk, const float* __restrict__ bk,
             const float* __restrict__ Wa, const float* __restrict__ ba,
             float* __restrict__ vOut, float* __restrict__ kOut,
             float* __restrict__ aOut)
{
    const int tid = threadIdx.x;
    const int c0  = tid & 63;                     // output col (per-lane)
    const int grp = tid >> 6;                     // 4 row-groups per block
    const int row0 = blockIdx.x * 16 + grp * 4;   // 512 blocks * 16 rows

    const float* wv = Wv + (size_t)c0 * IND;
    const float* wk = Wk + (size_t)c0 * IND;
    const float* wa = Wa + (size_t)c0 * IND;
    const float* xr0 = x + (size_t)(row0 + 0) * IND;
    const float* xr1 = x + (size_t)(row0 + 1) * IND;
    const float* xr2 = x + (size_t)(row0 + 2) * IND;
    const float* xr3 = x + (size_t)(row0 + 3) * IND;

    double a0[4] = {}, a1[4] = {}, a2[4] = {};

    for (int ko = 0; ko < IND; ko += 64) {
        float f0[4] = {}, f1[4] = {}, f2[4] = {};
        #pragma unroll
        for (int q = 0; q < 64; q += 4) {
            const int kk = ko + q;
            float4 w0 = *(const float4*)(wv + kk);
            float4 w1 = *(const float4*)(wk + kk);
            float4 w2 = *(const float4*)(wa + kk);
            float4 x0 = *(const float4*)(xr0 + kk);
            float4 x1 = *(const float4*)(xr1 + kk);
            float4 x2 = *(const float4*)(xr2 + kk);
            float4 x3 = *(const float4*)(xr3 + kk);
            // k ascending within each accumulator (matches R1/R6 bit-exactly)
            f0[0]=fmaf(x0.x,w0.x,f0[0]); f0[0]=fmaf(x0.y,w0.y,f0[0]); f0[0]=fmaf(x0.z,w0.z,f0[0]); f0[0]=fmaf(x0.w,w0.w,f0[0]);
            f0[1]=fmaf(x1.x,w0.x,f0[1]); f0[1]=fmaf(x1.y,w0.y,f0[1]); f0[1]=fmaf(x1.z,w0.z,f0[1]); f0[1]=fmaf(x1.w,w0.w,f0[1]);
            f0[2]=fmaf(x2.x,w0.x,f0[2]); f0[2]=fmaf(x2.y,w0.y,f0[2]); f0[2]=fmaf(x2.z,w0.z,f0[2]); f0[2]=fmaf(x2.w,w0.w,f0[2]);
            f0[3]=fmaf(x3.x,w0.x,f0[3]); f0[3]=fmaf(x3.y,w0.y,f0[3]); f0[3]=fmaf(x3.z,w0.z,f0[3]); f0[3]=fmaf(x3.w,w0.w,f0[3]);
            f1[0]=fmaf(x0.x,w1.x,f1[0]); f1[0]=fmaf(x0.y,w1.y,f1[0]); f1[0]=fmaf(x0.z,w1.z,f1[0]); f1[0]=fmaf(x0.w,w1.w,f1[0]);
            f1[1]=fmaf(x1.x,w1.x,f1[1]); f1[1]=fmaf(x1.y,w1.y,f1[1]); f1[1]=fmaf(x1.z,w1.z,f1[1]); f1[1]=fmaf(x1.w,w1.w,f1[1]);
            f1[2]=fmaf(x2.x,w1.x,f1[2]); f1[2]=fmaf(x2.y,w1.y,f1[2]); f1[2]=fmaf(x2.z,w1.z,f1[2]); f1[2]=fmaf(x2.w,w1.w,f1[2]);
            f1[3]=fmaf(x3.x,w1.x,f1[3]); f1[3]=fmaf(x3.y,w1.y,f1[3]); f1[3]=fmaf(x3.z,w1.z,f1[3]); f1[3]=fmaf(x3.w,w1.w,f1[3]);
            f2[0]=fmaf(x0.x,w2.x,f2[0]); f2[0]=fmaf(x0.y,w2.y,f2[0]); f2[0]=fmaf(x0.z,w2.z,f2[0]); f2[0]=fmaf(x0.w,w2.w,f2[0]);
            f2[1]=fmaf(x1.x,w2.x,f2[1]); f2[1]=fmaf(x1.y,w2.y,f2[1]); f2[1]=fmaf(x1.z,w2.z,f2[1]); f2[1]=fmaf(x1.w,w2.w,f2[1]);
            f2[2]=fmaf(x2.x,w2.x,f2[2]); f2[2]=fmaf(x2.y,w2.y,f2[2]); f2[2]=fmaf(x2.z,w2.z,f2[2]); f2[2]=fmaf(x2.w,w2.w,f2[2]);
            f2[3]=fmaf(x3.x,w2.x,f2[3]); f2[3]=fmaf(x3.y,w2.y,f2[3]); f2[3]=fmaf(x3.z,w2.z,f2[3]); f2[3]=fmaf(x3.w,w2.w,f2[3]);
        }
        #pragma unroll
        for (int i = 0; i < 4; ++i) { a0[i] += f0[i]; a1[i] += f1[i]; a2[i] += f2[i]; }
    }

    #pragma unroll
    for (int i = 0; i < 4; ++i) {
        size_t r = (size_t)row0 + i;
        vOut[r * 64 + c0] = (float)(a0[i] + (double)bv[c0]);
        kOut[r * 64 + c0] = (float)(a1[i] + (double)bk[c0]);
        double z = a2[i] + (double)ba[c0];
        aOut[r * 64 + c0] = (float)(1.0 / (1.0 + exp(-z)));
    }
}

// ---------------- K2a: per-chunk alpha products (R6 exact) ---------------------
__global__ __launch_bounds__(256)
void k2a_chunkprod(const float* __restrict__ alpha, double* __restrict__ cpA)
{
    int gt = blockIdx.x * 256 + threadIdx.x;      // 16384 = 32 chunks * 512 chains
    int ch = gt >> 9, chain = gt & 511;
    double p = 1.0;
    int base = (ch * CHL) * 512 + chain;
    #pragma unroll
    for (int i = 0; i < CHL; ++i) p *= (double)alpha[base + i * 512];
    cpA[gt] = p;
}

// ---------------- K2b: exclusive prefix product, register-staged (R6 exact) ----
__global__ __launch_bounds__(512)
void k2b_prefix(double* __restrict__ cpA)
{
    int chain = threadIdx.x;                      // 512 threads, 1 block
    double vals[NCH];
    #pragma unroll
    for (int ch = 0; ch < NCH; ++ch) vals[ch] = cpA[ch * 512 + chain];
    double run = 1.0;
    #pragma unroll
    for (int ch = 0; ch < NCH; ++ch) {
        cpA[ch * 512 + chain] = run;
        run *= vals[ch];
    }
}

// ---------------- K3: per-chunk partial C sums (R6 exact) ----------------------
__global__ __launch_bounds__(256)
void k3_csum(const float* __restrict__ vIn, const float* __restrict__ kIn,
             const float* __restrict__ alpha, const double* __restrict__ cpA,
             double* __restrict__ Csum)
{
    __shared__ double sV[CHL * 64];               // 16 KB
    const int tid = threadIdx.x;
    const int ch = blockIdx.x >> 3;
    const int b  = blockIdx.x & 7;
    #pragma unroll
    for (int q = 0; q < 8; ++q) {
        int idx = q * 256 + tid;
        int ti = idx >> 6, d = idx & 63;
        sV[idx] = (double)vIn[(((ch * CHL + ti) * BB) + b) * 64 + d];
    }
    __syncthreads();
    const int n = tid & 63;
    const int w = tid >> 6;
    double P = cpA[ch * 512 + b * 64 + n];
    double C[16];
    #pragma unroll
    for (int j = 0; j < 16; ++j) C[j] = 0.0;
    for (int i = 0; i < CHL; ++i) {
        int base = ((ch * CHL + i) * BB + b) * 64 + n;
        P *= (double)alpha[base];
        double invp = 1.0 / (P + EPSV);
        double kd = (double)kIn[base] * invp;
        const double* vrow = &sV[i * 64 + w * 16];
        #pragma unroll
        for (int j = 0; j < 16; ++j) C[j] = fma(vrow[j], kd, C[j]);
    }
    size_t cb = ((size_t)ch * 8 + b) * 4096 + (size_t)w * 1024 + n;
    #pragma unroll
    for (int j = 0; j < 16; ++j) Csum[cb + j * 64] = C[j];
}

// ---------------- K3b: exclusive prefix sum, register-staged (R6 exact) --------
__global__ __launch_bounds__(256)
void k3b_prefix(double* __restrict__ Csum)
{
    int s = blockIdx.x * 256 + threadIdx.x;       // 32768 chains
    int b = s >> 12, rest = s & 4095;
    double vals[NCH];
    #pragma unroll
    for (int ch = 0; ch < NCH; ++ch)
        vals[ch] = Csum[((size_t)ch * 8 + b) * 4096 + rest];
    double run = 0.0;
    #pragma unroll
    for (int ch = 0; ch < NCH; ++ch) {
        Csum[((size_t)ch * 8 + b) * 4096 + rest] = run;
        run += vals[ch];
    }
}

// ---------------- K4: main scan (R6 exact) -------------------------------------
__global__ __launch_bounds__(256)
void k4_scan(const float* __restrict__ vIn, const float* __restrict__ kIn,
             const float* __restrict__ alpha, const double* __restrict__ cpA,
             const double* __restrict__ Csum, float* __restrict__ outp)
{
    __shared__ double sV[CHL * 64];
    const int tid = threadIdx.x;
    const int ch = blockIdx.x >> 3;
    const int b  = blockIdx.x & 7;
    #pragma unroll
    for (int q = 0; q < 8; ++q) {
        int idx = q * 256 + tid;
        int ti = idx >> 6, d = idx & 63;
        sV[idx] = (double)vIn[(((ch * CHL + ti) * BB) + b) * 64 + d];
    }
    __syncthreads();
    const int n = tid & 63;
    const int w = tid >> 6;
    double P = cpA[ch * 512 + b * 64 + n];
    size_t cb = ((size_t)ch * 8 + b) * 4096 + (size_t)w * 1024 + n;
    double C[16];
    #pragma unroll
    for (int j = 0; j < 16; ++j) C[j] = Csum[cb + j * 64];

    float* spk = outp;
    float* mem = outp + OUTHALF;
    for (int i = 0; i < CHL; ++i) {
        int t = ch * CHL + i;
        int base = (t * BB + b) * 64 + n;
        P *= (double)alpha[base];
        double invp = 1.0 / (P + EPSV);
        double kd = (double)kIn[base] * invp;
        const double* vrow = &sV[i * 64 + w * 16];
        size_t ob = ((size_t)t * BB + b) * 4096 + (size_t)w * 1024 + n;
        #pragma unroll
        for (int j = 0; j < 16; ++j) {
            C[j] = fma(vrow[j], kd, C[j]);
            double S = P * C[j];
            mem[ob + j * 64] = (float)S;
            spk[ob + j * 64] = (S > 1.0) ? 1.0f : 0.0f;
        }
    }
}

// ---------------- launch -------------------------------------------------------
extern "C" void kernel_launch(void* const* d_in, const int* in_sizes, int n_in,
                              void* d_out, int out_size, void* d_ws, size_t ws_size,
                              hipStream_t stream)
{
    const float* x  = (const float*)d_in[0];
    const float* Wv = (const float*)d_in[1];
    const float* bv = (const float*)d_in[2];
    const float* Wk = (const float*)d_in[3];
    const float* bk = (const float*)d_in[4];
    const float* Wa = (const float*)d_in[5];
    const float* ba = (const float*)d_in[6];
    float* out = (float*)d_out;

    char* ws = (char*)d_ws;
    float*  v     = (float*)(ws);                                   // 2 MB
    float*  kk    = (float*)(ws + (2u << 20));                      // 2 MB
    float*  alpha = (float*)(ws + (4u << 20));                      // 2 MB
    double* cpA   = (double*)(ws + (6u << 20));                     // 128 KB
    double* Csum  = (double*)(ws + (7u << 20));                     // 8 MB

    hipLaunchKernelGGL(k1_proj,       dim3(512), dim3(256), 0, stream,
                       x, Wv, bv, Wk, bk, Wa, ba, v, kk, alpha);
    hipLaunchKernelGGL(k2a_chunkprod, dim3(64),  dim3(256), 0, stream, alpha, cpA);
    hipLaunchKernelGGL(k2b_prefix,    dim3(1),   dim3(512), 0, stream, cpA);
    hipLaunchKernelGGL(k3_csum,       dim3(256), dim3(256), 0, stream,
                       v, kk, alpha, cpA, Csum);
    hipLaunchKernelGGL(k3b_prefix,    dim3(128), dim3(256), 0, stream, Csum);
    hipLaunchKernelGGL(k4_scan,       dim3(256), dim3(256), 0, stream,
                       v, kk, alpha, cpA, Csum, out);
}

// Round 12
// 133.919 us; speedup vs baseline: 1.5929x; 1.5929x over previous
//
#include <hip/hip_runtime.h>
#include <cmath>

#define TT 1024
#define BB 8
#define IND 512
#define NCH 32
#define CHL 32          // TT / NCH
#define EPSV 1e-8
#define OUTHALF ((size_t)TT * BB * 4096)

// ---------------- K1: projections v,k,alpha — 8 rows/wave, 128-thr blocks ------
// Same 512-block grid and LDS tiles as R6; each wave now covers 8 rows via two
// broadcast b128 x-reads, amortizing the 3 per-lane w-reads over 24 FMA instead
// of 12. Per-element k-order and f64 chunk boundaries identical to R6
// -> bit-identical output.
__global__ __launch_bounds__(128)
void k1_proj(const float* __restrict__ x,
             const float* __restrict__ Wv, const float* __restrict__ bv,
             const float* __restrict__ Wk, const float* __restrict__ bk,
             const float* __restrict__ Wa, const float* __restrict__ ba,
             float* __restrict__ vOut, float* __restrict__ kOut,
             float* __restrict__ aOut)
{
    __shared__ float sWt[64][192];   // 48 KB, transposed weight chunk
    __shared__ float sXt[64][16];    // 4 KB,  transposed x chunk (16 rows)
    const int tid = threadIdx.x;
    const int rowbase = blockIdx.x * 16;          // 512 blocks * 16 rows = 8192
    const int c0 = tid & 63;                      // output col (per-lane)
    const int r0 = (tid >> 6) << 3;               // wave 0: rows 0-7, wave 1: 8-15
    double av[8] = {}, ak[8] = {}, aa[8] = {};

    for (int ko = 0; ko < IND; ko += 64) {
        __syncthreads();
        // stage W chunk (192 rows x 64 k), 128 threads -> 2 passes
        for (int s = tid; s < 192; s += 128) {
            const float* src = (s < 64  ? Wv + (size_t)s * IND
                              : s < 128 ? Wk + (size_t)(s - 64) * IND
                              :           Wa + (size_t)(s - 128) * IND) + ko;
            #pragma unroll
            for (int q = 0; q < 64; q += 4) {
                float4 w4 = *(const float4*)(src + q);
                sWt[q+0][s] = w4.x; sWt[q+1][s] = w4.y;
                sWt[q+2][s] = w4.z; sWt[q+3][s] = w4.w;
            }
        }
        // stage x chunk (16 rows x 64 k), 256 float4 slots, 128 threads -> 2 passes
        for (int s = tid; s < 256; s += 128) {
            int r  = s & 15;
            int kq = (s >> 4) << 2;               // 0,4,...,60
            float4 x4 = *(const float4*)(x + (size_t)(rowbase + r) * IND + ko + kq);
            sXt[kq+0][r] = x4.x; sXt[kq+1][r] = x4.y;
            sXt[kq+2][r] = x4.z; sXt[kq+3][r] = x4.w;
        }
        __syncthreads();

        float fv[8] = {}, fk[8] = {}, fa[8] = {};
        #pragma unroll
        for (int q = 0; q < 64; ++q) {
            float4 xa = *(const float4*)&sXt[q][r0];      // rows r0..r0+3 (bcast)
            float4 xb = *(const float4*)&sXt[q][r0 + 4];  // rows r0+4..r0+7
            float xr[8] = {xa.x, xa.y, xa.z, xa.w, xb.x, xb.y, xb.z, xb.w};
            float w0 = sWt[q][c0], w1 = sWt[q][c0 + 64], w2 = sWt[q][c0 + 128];
            #pragma unroll
            for (int j = 0; j < 8; ++j) {
                fv[j] = fmaf(xr[j], w0, fv[j]);
                fk[j] = fmaf(xr[j], w1, fk[j]);
                fa[j] = fmaf(xr[j], w2, fa[j]);
            }
        }
        #pragma unroll
        for (int j = 0; j < 8; ++j) { av[j] += fv[j]; ak[j] += fk[j]; aa[j] += fa[j]; }
    }

    #pragma unroll
    for (int j = 0; j < 8; ++j) {
        size_t r = (size_t)rowbase + r0 + j;
        vOut[r * 64 + c0] = (float)(av[j] + (double)bv[c0]);
        kOut[r * 64 + c0] = (float)(ak[j] + (double)bk[c0]);
        double z = aa[j] + (double)ba[c0];
        aOut[r * 64 + c0] = (float)(1.0 / (1.0 + exp(-z)));
    }
}

// ---------------- K2a: per-chunk alpha products (R6 exact) ---------------------
__global__ __launch_bounds__(256)
void k2a_chunkprod(const float* __restrict__ alpha, double* __restrict__ cpA)
{
    int gt = blockIdx.x * 256 + threadIdx.x;      // 16384 = 32 chunks * 512 chains
    int ch = gt >> 9, chain = gt & 511;
    double p = 1.0;
    int base = (ch * CHL) * 512 + chain;
    #pragma unroll
    for (int i = 0; i < CHL; ++i) p *= (double)alpha[base + i * 512];
    cpA[gt] = p;
}

// ---------------- K2b: exclusive prefix product, register-staged (R6 exact) ----
__global__ __launch_bounds__(512)
void k2b_prefix(double* __restrict__ cpA)
{
    int chain = threadIdx.x;                      // 512 threads, 1 block
    double vals[NCH];
    #pragma unroll
    for (int ch = 0; ch < NCH; ++ch) vals[ch] = cpA[ch * 512 + chain];
    double run = 1.0;
    #pragma unroll
    for (int ch = 0; ch < NCH; ++ch) {
        cpA[ch * 512 + chain] = run;
        run *= vals[ch];
    }
}

// ---------------- K3: per-chunk partial C sums (R6 exact) ----------------------
__global__ __launch_bounds__(256)
void k3_csum(const float* __restrict__ vIn, const float* __restrict__ kIn,
             const float* __restrict__ alpha, const double* __restrict__ cpA,
             double* __restrict__ Csum)
{
    __shared__ double sV[CHL * 64];               // 16 KB
    const int tid = threadIdx.x;
    const int ch = blockIdx.x >> 3;
    const int b  = blockIdx.x & 7;
    #pragma unroll
    for (int q = 0; q < 8; ++q) {
        int idx = q * 256 + tid;
        int ti = idx >> 6, d = idx & 63;
        sV[idx] = (double)vIn[(((ch * CHL + ti) * BB) + b) * 64 + d];
    }
    __syncthreads();
    const int n = tid & 63;
    const int w = tid >> 6;
    double P = cpA[ch * 512 + b * 64 + n];
    double C[16];
    #pragma unroll
    for (int j = 0; j < 16; ++j) C[j] = 0.0;
    for (int i = 0; i < CHL; ++i) {
        int base = ((ch * CHL + i) * BB + b) * 64 + n;
        P *= (double)alpha[base];
        double invp = 1.0 / (P + EPSV);
        double kd = (double)kIn[base] * invp;
        const double* vrow = &sV[i * 64 + w * 16];
        #pragma unroll
        for (int j = 0; j < 16; ++j) C[j] = fma(vrow[j], kd, C[j]);
    }
    size_t cb = ((size_t)ch * 8 + b) * 4096 + (size_t)w * 1024 + n;
    #pragma unroll
    for (int j = 0; j < 16; ++j) Csum[cb + j * 64] = C[j];
}

// ---------------- K3b: exclusive prefix sum, register-staged (R6 exact) --------
__global__ __launch_bounds__(256)
void k3b_prefix(double* __restrict__ Csum)
{
    int s = blockIdx.x * 256 + threadIdx.x;       // 32768 chains
    int b = s >> 12, rest = s & 4095;
    double vals[NCH];
    #pragma unroll
    for (int ch = 0; ch < NCH; ++ch)
        vals[ch] = Csum[((size_t)ch * 8 + b) * 4096 + rest];
    double run = 0.0;
    #pragma unroll
    for (int ch = 0; ch < NCH; ++ch) {
        Csum[((size_t)ch * 8 + b) * 4096 + rest] = run;
        run += vals[ch];
    }
}

// ---------------- K4: main scan (R6 exact) -------------------------------------
__global__ __launch_bounds__(256)
void k4_scan(const float* __restrict__ vIn, const float* __restrict__ kIn,
             const float* __restrict__ alpha, const double* __restrict__ cpA,
             const double* __restrict__ Csum, float* __restrict__ outp)
{
    __shared__ double sV[CHL * 64];
    const int tid = threadIdx.x;
    const int ch = blockIdx.x >> 3;
    const int b  = blockIdx.x & 7;
    #pragma unroll
    for (int q = 0; q < 8; ++q) {
        int idx = q * 256 + tid;
        int ti = idx >> 6, d = idx & 63;
        sV[idx] = (double)vIn[(((ch * CHL + ti) * BB) + b) * 64 + d];
    }
    __syncthreads();
    const int n = tid & 63;
    const int w = tid >> 6;
    double P = cpA[ch * 512 + b * 64 + n];
    size_t cb = ((size_t)ch * 8 + b) * 4096 + (size_t)w * 1024 + n;
    double C[16];
    #pragma unroll
    for (int j = 0; j < 16; ++j) C[j] = Csum[cb + j * 64];

    float* spk = outp;
    float* mem = outp + OUTHALF;
    for (int i = 0; i < CHL; ++i) {
        int t = ch * CHL + i;
        int base = (t * BB + b) * 64 + n;
        P *= (double)alpha[base];
        double invp = 1.0 / (P + EPSV);
        double kd = (double)kIn[base] * invp;
        const double* vrow = &sV[i * 64 + w * 16];
        size_t ob = ((size_t)t * BB + b) * 4096 + (size_t)w * 1024 + n;
        #pragma unroll
        for (int j = 0; j < 16; ++j) {
            C[j] = fma(vrow[j], kd, C[j]);
            double S = P * C[j];
            mem[ob + j * 64] = (float)S;
            spk[ob + j * 64] = (S > 1.0) ? 1.0f : 0.0f;
        }
    }
}

// ---------------- launch -------------------------------------------------------
extern "C" void kernel_launch(void* const* d_in, const int* in_sizes, int n_in,
                              void* d_out, int out_size, void* d_ws, size_t ws_size,
                              hipStream_t stream)
{
    const float* x  = (const float*)d_in[0];
    const float* Wv = (const float*)d_in[1];
    const float* bv = (const float*)d_in[2];
    const float* Wk = (const float*)d_in[3];
    const float* bk = (const float*)d_in[4];
    const float* Wa = (const float*)d_in[5];
    const float* ba = (const float*)d_in[6];
    float* out = (float*)d_out;

    char* ws = (char*)d_ws;
    float*  v     = (float*)(ws);                                   // 2 MB
    float*  kk    = (float*)(ws + (2u << 20));                      // 2 MB
    float*  alpha = (float*)(ws + (4u << 20));                      // 2 MB
    double* cpA   = (double*)(ws + (6u << 20));                     // 128 KB
    double* Csum  = (double*)(ws + (7u << 20));                     // 8 MB

    hipLaunchKernelGGL(k1_proj,       dim3(512), dim3(128), 0, stream,
                       x, Wv, bv, Wk, bk, Wa, ba, v, kk, alpha);
    hipLaunchKernelGGL(k2a_chunkprod, dim3(64),  dim3(256), 0, stream, alpha, cpA);
    hipLaunchKernelGGL(k2b_prefix,    dim3(1),   dim3(512), 0, stream, cpA);
    hipLaunchKernelGGL(k3_csum,       dim3(256), dim3(256), 0, stream,
                       v, kk, alpha, cpA, Csum);
    hipLaunchKernelGGL(k3b_prefix,    dim3(128), dim3(256), 0, stream, Csum);
    hipLaunchKernelGGL(k4_scan,       dim3(256), dim3(256), 0, stream,
                       v, kk, alpha, cpA, Csum, out);
}

// Round 13
// 122.417 us; speedup vs baseline: 1.7425x; 1.0940x over previous
//
#include <hip/hip_runtime.h>
#include <cmath>

#define TT 1024
#define BB 8
#define IND 512
#define NCH 32
#define CHL 32          // TT / NCH
#define EPSV 1e-8
#define OUTHALF ((size_t)TT * BB * 4096)

// ---------------- K1: projections — swizzled b128 W-reads ----------------------
// W chunk stored untransposed [192][64] with 16B-group XOR swizzle
// (phys_group = g ^ (row&7)): per-lane ds_read_b128 is conflict-free (lanes 0-7
// span all 32 banks). 3 LDS reads deliver 12 w-values for 4 q's (vs 12 b32 in
// R6). x stays transposed+broadcast. FMA order/f64 chunking identical to R6
// -> bit-identical output.
__global__ __launch_bounds__(256)
void k1_proj(const float* __restrict__ x,
             const float* __restrict__ Wv, const float* __restrict__ bv,
             const float* __restrict__ Wk, const float* __restrict__ bk,
             const float* __restrict__ Wa, const float* __restrict__ ba,
             float* __restrict__ vOut, float* __restrict__ kOut,
             float* __restrict__ aOut)
{
    __shared__ float sW[192][64];    // 48 KB, swizzled 16B groups
    __shared__ float sXt[64][16];    // 4 KB, transposed x chunk
    const int tid = threadIdx.x;
    const int rowbase = blockIdx.x * 16;          // 512 blocks * 16 rows = 8192
    const int c0 = tid & 63;                      // output col (per-lane)
    const int r0 = (tid >> 6) << 2;               // 4 rows per thread
    const int xr7 = c0 & 7;                       // read-side XOR bits
    double a0[4] = {}, a1[4] = {}, a2[4] = {};

    for (int ko = 0; ko < IND; ko += 64) {
        __syncthreads();
        // stage W chunk: 192 rows x 16 groups, b128 global -> b128 swizzled LDS
        #pragma unroll
        for (int it = 0; it < 12; ++it) {
            int idx = it * 256 + tid;             // 0..3071
            int s = idx >> 4;                     // row 0..191
            int g = idx & 15;                     // logical 16B group
            const float* src = (s < 64  ? Wv + (size_t)s * IND
                              : s < 128 ? Wk + (size_t)(s - 64) * IND
                              :           Wa + (size_t)(s - 128) * IND) + ko + g * 4;
            float4 w4 = *(const float4*)src;
            *(float4*)&sW[s][(g ^ (s & 7)) * 4] = w4;
        }
        // stage x chunk (16 rows x 64 k), transposed, 1 float4/thread
        {
            int r  = tid & 15;
            int kq = (tid >> 4) << 2;
            float4 x4 = *(const float4*)(x + (size_t)(rowbase + r) * IND + ko + kq);
            sXt[kq+0][r] = x4.x; sXt[kq+1][r] = x4.y;
            sXt[kq+2][r] = x4.z; sXt[kq+3][r] = x4.w;
        }
        __syncthreads();

        float f0[4] = {}, f1[4] = {}, f2[4] = {};
        #pragma unroll
        for (int g = 0; g < 16; ++g) {
            const int pg = (g ^ xr7) * 4;
            float4 w0 = *(const float4*)&sW[c0      ][pg];   // W[c0][4g..4g+3]
            float4 w1 = *(const float4*)&sW[c0 + 64 ][pg];
            float4 w2 = *(const float4*)&sW[c0 + 128][pg];
            float4 xq0 = *(const float4*)&sXt[4*g+0][r0];    // rows r0..r0+3
            float4 xq1 = *(const float4*)&sXt[4*g+1][r0];
            float4 xq2 = *(const float4*)&sXt[4*g+2][r0];
            float4 xq3 = *(const float4*)&sXt[4*g+3][r0];
            // q = 4g+0 .. 4g+3, ascending (bit-identical to R6)
            f0[0]=fmaf(xq0.x,w0.x,f0[0]); f1[0]=fmaf(xq0.x,w1.x,f1[0]); f2[0]=fmaf(xq0.x,w2.x,f2[0]);
            f0[1]=fmaf(xq0.y,w0.x,f0[1]); f1[1]=fmaf(xq0.y,w1.x,f1[1]); f2[1]=fmaf(xq0.y,w2.x,f2[1]);
            f0[2]=fmaf(xq0.z,w0.x,f0[2]); f1[2]=fmaf(xq0.z,w1.x,f1[2]); f2[2]=fmaf(xq0.z,w2.x,f2[2]);
            f0[3]=fmaf(xq0.w,w0.x,f0[3]); f1[3]=fmaf(xq0.w,w1.x,f1[3]); f2[3]=fmaf(xq0.w,w2.x,f2[3]);

            f0[0]=fmaf(xq1.x,w0.y,f0[0]); f1[0]=fmaf(xq1.x,w1.y,f1[0]); f2[0]=fmaf(xq1.x,w2.y,f2[0]);
            f0[1]=fmaf(xq1.y,w0.y,f0[1]); f1[1]=fmaf(xq1.y,w1.y,f1[1]); f2[1]=fmaf(xq1.y,w2.y,f2[1]);
            f0[2]=fmaf(xq1.z,w0.y,f0[2]); f1[2]=fmaf(xq1.z,w1.y,f1[2]); f2[2]=fmaf(xq1.z,w2.y,f2[2]);
            f0[3]=fmaf(xq1.w,w0.y,f0[3]); f1[3]=fmaf(xq1.w,w1.y,f1[3]); f2[3]=fmaf(xq1.w,w2.y,f2[3]);

            f0[0]=fmaf(xq2.x,w0.z,f0[0]); f1[0]=fmaf(xq2.x,w1.z,f1[0]); f2[0]=fmaf(xq2.x,w2.z,f2[0]);
            f0[1]=fmaf(xq2.y,w0.z,f0[1]); f1[1]=fmaf(xq2.y,w1.z,f1[1]); f2[1]=fmaf(xq2.y,w2.z,f2[1]);
            f0[2]=fmaf(xq2.z,w0.z,f0[2]); f1[2]=fmaf(xq2.z,w1.z,f1[2]); f2[2]=fmaf(xq2.z,w2.z,f2[2]);
            f0[3]=fmaf(xq2.w,w0.z,f0[3]); f1[3]=fmaf(xq2.w,w1.z,f1[3]); f2[3]=fmaf(xq2.w,w2.z,f2[3]);

            f0[0]=fmaf(xq3.x,w0.w,f0[0]); f1[0]=fmaf(xq3.x,w1.w,f1[0]); f2[0]=fmaf(xq3.x,w2.w,f2[0]);
            f0[1]=fmaf(xq3.y,w0.w,f0[1]); f1[1]=fmaf(xq3.y,w1.w,f1[1]); f2[1]=fmaf(xq3.y,w2.w,f2[1]);
            f0[2]=fmaf(xq3.z,w0.w,f0[2]); f1[2]=fmaf(xq3.z,w1.w,f1[2]); f2[2]=fmaf(xq3.z,w2.w,f2[2]);
            f0[3]=fmaf(xq3.w,w0.w,f0[3]); f1[3]=fmaf(xq3.w,w1.w,f1[3]); f2[3]=fmaf(xq3.w,w2.w,f2[3]);
        }
        #pragma unroll
        for (int i = 0; i < 4; ++i) { a0[i] += f0[i]; a1[i] += f1[i]; a2[i] += f2[i]; }
    }

    #pragma unroll
    for (int i = 0; i < 4; ++i) {
        int r = rowbase + r0 + i;
        vOut[r * 64 + c0] = (float)(a0[i] + (double)bv[c0]);
        kOut[r * 64 + c0] = (float)(a1[i] + (double)bk[c0]);
        double z = a2[i] + (double)ba[c0];
        aOut[r * 64 + c0] = (float)(1.0 / (1.0 + exp(-z)));
    }
}

// ---------------- K2a: per-chunk alpha products (R6 exact) ---------------------
__global__ __launch_bounds__(256)
void k2a_chunkprod(const float* __restrict__ alpha, double* __restrict__ cpA)
{
    int gt = blockIdx.x * 256 + threadIdx.x;      // 16384 = 32 chunks * 512 chains
    int ch = gt >> 9, chain = gt & 511;
    double p = 1.0;
    int base = (ch * CHL) * 512 + chain;
    #pragma unroll
    for (int i = 0; i < CHL; ++i) p *= (double)alpha[base + i * 512];
    cpA[gt] = p;
}

// ---------------- K2b: exclusive prefix product, register-staged (R6 exact) ----
__global__ __launch_bounds__(512)
void k2b_prefix(double* __restrict__ cpA)
{
    int chain = threadIdx.x;                      // 512 threads, 1 block
    double vals[NCH];
    #pragma unroll
    for (int ch = 0; ch < NCH; ++ch) vals[ch] = cpA[ch * 512 + chain];
    double run = 1.0;
    #pragma unroll
    for (int ch = 0; ch < NCH; ++ch) {
        cpA[ch * 512 + chain] = run;
        run *= vals[ch];
    }
}

// ---------------- K3: per-chunk partial C sums (R6 exact) ----------------------
__global__ __launch_bounds__(256)
void k3_csum(const float* __restrict__ vIn, const float* __restrict__ kIn,
             const float* __restrict__ alpha, const double* __restrict__ cpA,
             double* __restrict__ Csum)
{
    __shared__ double sV[CHL * 64];               // 16 KB
    const int tid = threadIdx.x;
    const int ch = blockIdx.x >> 3;
    const int b  = blockIdx.x & 7;
    #pragma unroll
    for (int q = 0; q < 8; ++q) {
        int idx = q * 256 + tid;
        int ti = idx >> 6, d = idx & 63;
        sV[idx] = (double)vIn[(((ch * CHL + ti) * BB) + b) * 64 + d];
    }
    __syncthreads();
    const int n = tid & 63;
    const int w = tid >> 6;
    double P = cpA[ch * 512 + b * 64 + n];
    double C[16];
    #pragma unroll
    for (int j = 0; j < 16; ++j) C[j] = 0.0;
    for (int i = 0; i < CHL; ++i) {
        int base = ((ch * CHL + i) * BB + b) * 64 + n;
        P *= (double)alpha[base];
        double invp = 1.0 / (P + EPSV);
        double kd = (double)kIn[base] * invp;
        const double* vrow = &sV[i * 64 + w * 16];
        #pragma unroll
        for (int j = 0; j < 16; ++j) C[j] = fma(vrow[j], kd, C[j]);
    }
    size_t cb = ((size_t)ch * 8 + b) * 4096 + (size_t)w * 1024 + n;
    #pragma unroll
    for (int j = 0; j < 16; ++j) Csum[cb + j * 64] = C[j];
}

// ---------------- K3b: exclusive prefix sum, register-staged (R6 exact) --------
__global__ __launch_bounds__(256)
void k3b_prefix(double* __restrict__ Csum)
{
    int s = blockIdx.x * 256 + threadIdx.x;       // 32768 chains
    int b = s >> 12, rest = s & 4095;
    double vals[NCH];
    #pragma unroll
    for (int ch = 0; ch < NCH; ++ch)
        vals[ch] = Csum[((size_t)ch * 8 + b) * 4096 + rest];
    double run = 0.0;
    #pragma unroll
    for (int ch = 0; ch < NCH; ++ch) {
        Csum[((size_t)ch * 8 + b) * 4096 + rest] = run;
        run += vals[ch];
    }
}

// ---------------- K4: main scan (R6 exact) -------------------------------------
__global__ __launch_bounds__(256)
void k4_scan(const float* __restrict__ vIn, const float* __restrict__ kIn,
             const float* __restrict__ alpha, const double* __restrict__ cpA,
             const double* __restrict__ Csum, float* __restrict__ outp)
{
    __shared__ double sV[CHL * 64];
    const int tid = threadIdx.x;
    const int ch = blockIdx.x >> 3;
    const int b  = blockIdx.x & 7;
    #pragma unroll
    for (int q = 0; q < 8; ++q) {
        int idx = q * 256 + tid;
        int ti = idx >> 6, d = idx & 63;
        sV[idx] = (double)vIn[(((ch * CHL + ti) * BB) + b) * 64 + d];
    }
    __syncthreads();
    const int n = tid & 63;
    const int w = tid >> 6;
    double P = cpA[ch * 512 + b * 64 + n];
    size_t cb = ((size_t)ch * 8 + b) * 4096 + (size_t)w * 1024 + n;
    double C[16];
    #pragma unroll
    for (int j = 0; j < 16; ++j) C[j] = Csum[cb + j * 64];

    float* spk = outp;
    float* mem = outp + OUTHALF;
    for (int i = 0; i < CHL; ++i) {
        int t = ch * CHL + i;
        int base = (t * BB + b) * 64 + n;
        P *= (double)alpha[base];
        double invp = 1.0 / (P + EPSV);
        double kd = (double)kIn[base] * invp;
        const double* vrow = &sV[i * 64 + w * 16];
        size_t ob = ((size_t)t * BB + b) * 4096 + (size_t)w * 1024 + n;
        #pragma unroll
        for (int j = 0; j < 16; ++j) {
            C[j] = fma(vrow[j], kd, C[j]);
            double S = P * C[j];
            mem[ob + j * 64] = (float)S;
            spk[ob + j * 64] = (S > 1.0) ? 1.0f : 0.0f;
        }
    }
}

// ---------------- launch -------------------------------------------------------
extern "C" void kernel_launch(void* const* d_in, const int* in_sizes, int n_in,
                              void* d_out, int out_size, void* d_ws, size_t ws_size,
                              hipStream_t stream)
{
    const float* x  = (const float*)d_in[0];
    const float* Wv = (const float*)d_in[1];
    const float* bv = (const float*)d_in[2];
    const float* Wk = (const float*)d_in[3];
    const float* bk = (const float*)d_in[4];
    const float* Wa = (const float*)d_in[5];
    const float* ba = (const float*)d_in[6];
    float* out = (float*)d_out;

    char* ws = (char*)d_ws;
    float*  v     = (float*)(ws);                                   // 2 MB
    float*  kk    = (float*)(ws + (2u << 20));                      // 2 MB
    float*  alpha = (float*)(ws + (4u << 20));                      // 2 MB
    double* cpA   = (double*)(ws + (6u << 20));                     // 128 KB
    double* Csum  = (double*)(ws + (7u << 20));                     // 8 MB

    hipLaunchKernelGGL(k1_proj,       dim3(512), dim3(256), 0, stream,
                       x, Wv, bv, Wk, bk, Wa, ba, v, kk, alpha);
    hipLaunchKernelGGL(k2a_chunkprod, dim3(64),  dim3(256), 0, stream, alpha, cpA);
    hipLaunchKernelGGL(k2b_prefix,    dim3(1),   dim3(512), 0, stream, cpA);
    hipLaunchKernelGGL(k3_csum,       dim3(256), dim3(256), 0, stream,
                       v, kk, alpha, cpA, Csum);
    hipLaunchKernelGGL(k3b_prefix,    dim3(128), dim3(256), 0, stream, Csum);
    hipLaunchKernelGGL(k4_scan,       dim3(256), dim3(256), 0, stream,
                       v, kk, alpha, cpA, Csum, out);
}